// Round 13
// baseline (9491.924 us; speedup 1.0000x reference)
//
#include <hip/hip_runtime.h>

#define NSTATE 16
#define H1 75
#define CHUNK 384            // 128 triples per chunk (ring of 4 divides 128)
#define NTRIC (CHUNK / 3)    // 128
#define CFLOATS (NTRIC * 64) // Q' floats per chunk (8192 = 32KB)
#define HROW 36              // hist2 row stride in dwords (8*4 + 4 pad)

// exact numpy-f32 prior: mul+add (NOT fma) layer 1, sequential-k FMA layer 2.
#define PRIOR_ONE(rxv, jj, dst)                               \
  {                                                           \
    float acc = 0.f;                                          \
    for (int k = 0; k < H1; ++k) {                            \
      float h = __fadd_rn(__fmul_rn((rxv), W1[k]), b1[k]);    \
      h = fmaxf(h, 0.f);                                      \
      acc = __fmaf_rn(h, W2[k * NSTATE + (jj)], acc);         \
    }                                                         \
    (dst) = __fadd_rn(acc, b2[(jj)]);                         \
  }

#define DPP_SWAP(x, CTRL) \
  __int_as_float(__builtin_amdgcn_mov_dpp(__float_as_int(x), (CTRL), 0xF, 0xF, true))

// async global->LDS, 16B per lane, wave-uniform LDS base (HW layout contract)
#define GL2LDS(g, l)                                              \
  __builtin_amdgcn_global_load_lds(                               \
      (const __attribute__((address_space(1))) void*)(g),         \
      (__attribute__((address_space(3))) void*)(l), 16, 0, 0)

// strict-< first-occurrence argmin parity over u[0..7] read via LUT'd lanes
#define BITS_FROM_HIST2(HBASE, tl, OUTEXPR)                                  \
  {                                                                          \
    const int n_ = (tl) / 3, ph_ = (tl) - 3 * n_;                            \
    const float* hrow = (HBASE) + n_ * HROW + ph_;                           \
    const unsigned word = (ph_ == 0) ? 0x76543210u                           \
                        : (ph_ == 1) ? 0x75316420u : 0x73625140u;            \
    float m = hrow[((word >> 0) & 7) * 4]; int arg = 0;                      \
    { const float x = hrow[((word >> 4) & 7) * 4];  if (x < m) { m = x; arg = 1; } } \
    { const float x = hrow[((word >> 8) & 7) * 4];  if (x < m) { m = x; arg = 2; } } \
    { const float x = hrow[((word >> 12) & 7) * 4]; if (x < m) { m = x; arg = 3; } } \
    { const float x = hrow[((word >> 16) & 7) * 4]; if (x < m) { m = x; arg = 4; } } \
    { const float x = hrow[((word >> 20) & 7) * 4]; if (x < m) { m = x; arg = 5; } } \
    { const float x = hrow[((word >> 24) & 7) * 4]; if (x < m) { m = x; arg = 6; } } \
    { const float x = hrow[((word >> 28) & 7) * 4]; if (x < m) { m = x; arg = 7; } } \
    (OUTEXPR) = (float)(arg & 1);                                            \
  }

// ---------- K1: priors, grid-wide, stored triple-blocked + pre-swapped -----
// (unchanged from r11/r12, both passing)
__global__ void priors_kernel(const float* __restrict__ rx,
                              const float* __restrict__ W1,
                              const float* __restrict__ b1,
                              const float* __restrict__ W2,
                              const float* __restrict__ b2,
                              float* __restrict__ q, int T, int tot) {
  const int id = blockIdx.x * 256 + threadIdx.x;  // id = t*16 + j
  if (id >= tot) return;
  const int t = id >> 4, j = id & 15;
  float val = 0.f;
  if (t < T) {
    const float rxv = rx[t];
    PRIOR_ONE(rxv, j, val);
  }
  const int n = t / 3, ph = t - 3 * n;
  const int s = j >> 1, b = j & 1, r = (s >> 2) & 1;
  const int i3 = (ph == 0) ? (((s << 1) | (s >> 2)) & 7)
               : (ph == 1) ? (((s >> 1) | (s << 2)) & 7) : s;
  const int slot = 2 * ph + (b ^ r);
  q[(size_t)n * 64 + i3 * 8 + slot] = val;
}

// ---------- K2: serial ACS + copy + bits, 3 waves ---------------------------
// wave 0: butterfly; per triple: 2 ds_reads (ring) + ONE predicated
//         ds_write_b128 of {w@ph0,w@ph1,w@ph2,0} (was 3 writes + junk).
// wave 1: async copy chunk c+1 global -> q_lds[1-p] (r12-proven).
// wave 2: bits for chunk c-1 from hist2[1-p] via phase->lane LUT.
__launch_bounds__(192, 1)
__global__ void acs3_kernel(const float* __restrict__ q,
                            float* __restrict__ out, int T, int nchunks) {
  __shared__ float q_lds[2][CFLOATS];          // 64 KB
  __shared__ float hist2[2][NTRIC * HROW];     // 36.9 KB
  const int tid = (int)threadIdx.x;
  const int lane = tid & 63;
  const int wid = tid >> 6;

  // ---- prologue: copy chunk 0 into q_lds[0] (all 192 threads) ----
  {
    const float4* src = (const float4*)q;
    float4* dst = (float4*)&q_lds[0][0];
    for (int i = tid; i < CFLOATS / 4; i += 192) dst[i] = src[i];
  }
  __syncthreads();

  // ---- per-lane butterfly constants (r8/r10-verified) ----
  const int i3 = (lane & 3) | ((lane >> 1) & 4);
  const bool dumper = (lane < 16) && ((lane & 4) == 0);

  float w = 0.f;  // S[i] = u[i] at phase 0

  for (int c = 0; c < nchunks; ++c) {
    const int p = c & 1;

    if (wid == 0) {
      // ---- wave 0: serial butterfly over 128 triples ----
      const char* qptr = (const char*)(&q_lds[p][0] + i3 * 8);
      char* hb = (char*)&hist2[p][0] + i3 * 16;   // + triple*144 below

      float4 rA[4]; float2 rB[4];  // ring: 4 triples in flight
#pragma unroll
      for (int n = 0; n < 4; ++n) {
        rA[n] = *(const float4*)(qptr + n * 256);
        rB[n] = *(const float2*)(qptr + n * 256 + 16);
      }
      for (int it = 0; it < NTRIC / 4 - 1; ++it) {  // 31 iters: triples 0..123
#pragma unroll
        for (int n = 0; n < 4; ++n) {
          const float4 A = rA[n]; const float2 B = rB[n];
          rA[n] = *(const float4*)(qptr + (n + 4) * 256);
          rB[n] = *(const float2*)(qptr + (n + 4) * 256 + 16);
          float4 hv;
          hv.x = w;
          { const float wp = DPP_SWAP(w, 0xB1);   // lane^1
            w = fminf(__fsub_rn(w, A.x), __fsub_rn(wp, A.y)); }
          hv.y = w;
          { const float wp = DPP_SWAP(w, 0x4E);   // lane^2
            w = fminf(__fsub_rn(w, A.z), __fsub_rn(wp, A.w)); }
          hv.z = w;
          hv.w = 0.f;
          if (dumper) *(float4*)(hb + n * 144) = hv;
          { const float wp = DPP_SWAP(w, 0x128);  // lane^8 (row_ror:8)
            w = fminf(__fsub_rn(w, B.x), __fsub_rn(wp, B.y)); }
        }
        qptr += 1024; hb += 576;
      }
#pragma unroll
      for (int n = 0; n < 4; ++n) {  // epilogue: triples 124..127, no reload
        const float4 A = rA[n]; const float2 B = rB[n];
        float4 hv;
        hv.x = w;
        { const float wp = DPP_SWAP(w, 0xB1);
          w = fminf(__fsub_rn(w, A.x), __fsub_rn(wp, A.y)); }
        hv.y = w;
        { const float wp = DPP_SWAP(w, 0x4E);
          w = fminf(__fsub_rn(w, A.z), __fsub_rn(wp, A.w)); }
        hv.z = w;
        hv.w = 0.f;
        if (dumper) *(float4*)(hb + n * 144) = hv;
        { const float wp = DPP_SWAP(w, 0x128);
          w = fminf(__fsub_rn(w, B.x), __fsub_rn(wp, B.y)); }
      }
    } else if (wid == 1) {
      // ---- wave 1: async copy chunk c+1 global -> q_lds[1-p] ----
      if (c + 1 < nchunks) {
        const float* srcbase = q + (size_t)(c + 1) * CFLOATS + lane * 4;
        float* const ldsbase = &q_lds[1 - p][0];
#pragma unroll
        for (int i = 0; i < CFLOATS / 256; ++i) {   // 32 x 1KB, all in flight
          GL2LDS(srcbase + i * 256, ldsbase + i * 256);
        }
        asm volatile("s_waitcnt vmcnt(0)" ::: "memory");
      }
    } else {
      // ---- wave 2: bits for chunk c-1 ----
      if (c > 0) {
        const float* hbase = &hist2[1 - p][0];
        for (int tl = lane; tl < CHUNK; tl += 64) {
          BITS_FROM_HIST2(hbase, tl, out[(c - 1) * CHUNK + tl]);
        }
      }
    }
    __syncthreads();
  }

  // ---- epilogue: bits for the last chunk (all 192 threads) ----
  {
    const int c = nchunks - 1;
    const int p = c & 1;
    const int base = c * CHUNK;
    const int nsteps = T - base;
    const float* hbase = &hist2[p][0];
    for (int tl = tid; tl < nsteps; tl += 192) {
      BITS_FROM_HIST2(hbase, tl, out[base + tl]);
    }
  }
}

// ---------- Fallback: round-8 single-kernel structure (PASSING lineage) -----
#define NPROD 960
__launch_bounds__(1024, 1)
__global__ void viterbi_bfly(const float* __restrict__ rx,
                             const float* __restrict__ W1,
                             const float* __restrict__ b1,
                             const float* __restrict__ W2,
                             const float* __restrict__ b2,
                             float* __restrict__ out, int T) {
  __shared__ float q_lds[2][CHUNK][NSTATE];
  __shared__ float hist[2][CHUNK][9];
  const int tid = (int)threadIdx.x;
  const int lane = tid & 63;
  const int j = tid & 15;
  const int nchunks = (T + CHUNK - 1) / CHUNK;
  {
    const int n0 = min(CHUNK, T);
    for (int id = tid; id < n0 * NSTATE; id += 1024) {
      const int tl = id >> 4;
      const float rxv = rx[tl];
      PRIOR_ONE(rxv, j, q_lds[0][tl][j]);
    }
  }
  __syncthreads();
  const int i3 = (lane & 3) | ((lane >> 1) & 4);
  const int rotr_i = ((i3 >> 1) | (i3 << 2)) & 7;
  const int rotl_i = ((i3 << 1) | (i3 >> 2)) & 7;
  const int s0 = rotr_i, s1 = rotl_i, s2 = i3;
  const int q0 = 2 * s0, q1 = 2 * s1, q2 = 2 * s2;
  const bool r0 = (s0 & 4) != 0, r1 = (s1 & 4) != 0, r2 = (s2 & 4) != 0;
  const int d0 = i3, d1 = rotr_i, d2 = rotl_i;
  const bool dumper = (lane < 16) && ((lane & 4) == 0);
  float w = 0.f;
  for (int c = 0; c < nchunks; ++c) {
    const int p = c & 1;
    const int base = c * CHUNK;
    const int nsteps = min(CHUNK, T - base);
    const int npad = ((nsteps + 2) / 3) * 3;
    if (tid < 64) {
      const float* qb = &q_lds[p][0][0];
      float2 f0 = *(const float2*)(qb + 0 * 16 + q0);
      float2 f1 = *(const float2*)(qb + 1 * 16 + q1);
      float2 f2 = *(const float2*)(qb + 2 * 16 + q2);
      for (int tl = 0; tl < npad; tl += 3) {
        const int nt = min(tl + 3, CHUNK - 3);
        float2 g0 = *(const float2*)(qb + (nt + 0) * 16 + q0);
        float2 g1 = *(const float2*)(qb + (nt + 1) * 16 + q1);
        float2 g2 = *(const float2*)(qb + (nt + 2) * 16 + q2);
        if (dumper) hist[p][tl][d0] = w;
        {
          const float wp = DPP_SWAP(w, 0xB1);
          const float we = r0 ? wp : w, wo = r0 ? w : wp;
          w = fminf(__fsub_rn(we, f0.x), __fsub_rn(wo, f0.y));
        }
        if (dumper) hist[p][tl + 1][d1] = w;
        {
          const float wp = DPP_SWAP(w, 0x4E);
          const float we = r1 ? wp : w, wo = r1 ? w : wp;
          w = fminf(__fsub_rn(we, f1.x), __fsub_rn(wo, f1.y));
        }
        if (dumper) hist[p][tl + 2][d2] = w;
        {
          const float wp = DPP_SWAP(w, 0x128);
          const float we = r2 ? wp : w, wo = r2 ? w : wp;
          w = fminf(__fsub_rn(we, f2.x), __fsub_rn(wo, f2.y));
        }
        f0 = g0; f1 = g1; f2 = g2;
      }
    } else {
      const int nc = c + 1;
      if (nc < nchunks) {
        const int nbase = nc * CHUNK;
        const int nn = min(CHUNK, T - nbase);
        for (int id = tid - 64; id < nn * NSTATE; id += NPROD) {
          const int tl = id >> 4;
          const float rxv = rx[nbase + tl];
          PRIOR_ONE(rxv, j, q_lds[1 - p][tl][j]);
        }
      }
      if (c > 0) {
        const int tl = tid - 64;
        if (tl < CHUNK) {
          const float* h = hist[1 - p][tl];
          float m = h[0]; int arg = 0;
          if (h[1] < m) { m = h[1]; arg = 1; }
          if (h[2] < m) { m = h[2]; arg = 2; }
          if (h[3] < m) { m = h[3]; arg = 3; }
          if (h[4] < m) { m = h[4]; arg = 4; }
          if (h[5] < m) { m = h[5]; arg = 5; }
          if (h[6] < m) { m = h[6]; arg = 6; }
          if (h[7] < m) { m = h[7]; arg = 7; }
          out[(c - 1) * CHUNK + tl] = (float)(arg & 1);
        }
      }
    }
    __syncthreads();
  }
  {
    const int c = nchunks - 1;
    const int p = c & 1;
    const int base = c * CHUNK;
    const int nsteps = T - base;
    if (tid < nsteps) {
      const float* h = hist[p][tid];
      float m = h[0]; int arg = 0;
      if (h[1] < m) { m = h[1]; arg = 1; }
      if (h[2] < m) { m = h[2]; arg = 2; }
      if (h[3] < m) { m = h[3]; arg = 3; }
      if (h[4] < m) { m = h[4]; arg = 4; }
      if (h[5] < m) { m = h[5]; arg = 5; }
      if (h[6] < m) { m = h[6]; arg = 6; }
      if (h[7] < m) { m = h[7]; arg = 7; }
      out[base + tid] = (float)(arg & 1);
    }
  }
}

extern "C" void kernel_launch(void* const* d_in, const int* in_sizes, int n_in,
                              void* d_out, int out_size, void* d_ws, size_t ws_size,
                              hipStream_t stream) {
  const float* rx = (const float*)d_in[0];
  const float* W1 = (const float*)d_in[1];
  const float* b1 = (const float*)d_in[2];
  const float* W2 = (const float*)d_in[3];
  const float* b2 = (const float*)d_in[4];
  float* out = (float*)d_out;
  const int T = in_sizes[0];

  const int nchunks = (T + CHUNK - 1) / CHUNK;
  const int tot = nchunks * CHUNK * NSTATE;              // K1 thread count
  const size_t need = (size_t)nchunks * CFLOATS * 4;     // FULL padded q size

  if (ws_size >= need) {
    float* qws = (float*)d_ws;
    priors_kernel<<<(tot + 255) / 256, 256, 0, stream>>>(
        rx, W1, b1, W2, b2, qws, T, tot);
    acs3_kernel<<<1, 192, 0, stream>>>(qws, out, T, nchunks);
  } else {
    viterbi_bfly<<<1, 1024, 0, stream>>>(rx, W1, b1, W2, b2, out, T);
  }
}

// Round 14
// 8261.082 us; speedup vs baseline: 1.1490x; 1.1490x over previous
//
#include <hip/hip_runtime.h>

#define NSTATE 16
#define H1 75
#define CHUNK 480            // 160 triples; %3==0, %16==0 (gl2lds), ring 4 | 160
#define NTRIC (CHUNK / 3)    // 160
#define CFLOATS (NTRIC * 64) // 10240 floats = 40 KB per buffer

// exact numpy-f32 prior: mul+add (NOT fma) layer 1, sequential-k FMA layer 2.
#define PRIOR_ONE(rxv, jj, dst)                               \
  {                                                           \
    float acc = 0.f;                                          \
    for (int k = 0; k < H1; ++k) {                            \
      float h = __fadd_rn(__fmul_rn((rxv), W1[k]), b1[k]);    \
      h = fmaxf(h, 0.f);                                      \
      acc = __fmaf_rn(h, W2[k * NSTATE + (jj)], acc);         \
    }                                                         \
    (dst) = __fadd_rn(acc, b2[(jj)]);                         \
  }

#define DPP_SWAP(x, CTRL) \
  __int_as_float(__builtin_amdgcn_mov_dpp(__float_as_int(x), (CTRL), 0xF, 0xF, true))

// async global->LDS, 16B per lane, wave-uniform LDS base (HW layout contract)
#define GL2LDS(g, l)                                              \
  __builtin_amdgcn_global_load_lds(                               \
      (const __attribute__((address_space(1))) void*)(g),         \
      (__attribute__((address_space(3))) void*)(l), 16, 0, 0)

// ---------- K1: priors, grid-wide, stored triple-blocked + pre-swapped -----
// Q'[n][i3][slot]: slots 0-1 = phase-0 pair, 2-3 = phase-1, 4-5 = phase-2
// (6,7 pad), pair pre-swapped by r = bit2(state) (r10..r13-proven).
__global__ void priors_kernel(const float* __restrict__ rx,
                              const float* __restrict__ W1,
                              const float* __restrict__ b1,
                              const float* __restrict__ W2,
                              const float* __restrict__ b2,
                              float* __restrict__ q, int T, int tot) {
  const int id = blockIdx.x * 256 + threadIdx.x;  // id = t*16 + j
  if (id >= tot) return;
  const int t = id >> 4, j = id & 15;
  float val = 0.f;
  if (t < T) {
    const float rxv = rx[t];
    PRIOR_ONE(rxv, j, val);
  }
  const int n = t / 3, ph = t - 3 * n;
  const int s = j >> 1, b = j & 1, r = (s >> 2) & 1;
  const int i3 = (ph == 0) ? (((s << 1) | (s >> 2)) & 7)
               : (ph == 1) ? (((s >> 1) | (s << 2)) & 7) : s;
  const int slot = 2 * ph + (b ^ r);
  q[(size_t)n * 64 + i3 * 8 + slot] = val;
}

// ---------- K2: serial ACS + copy + bits, 3 waves ---------------------------
// Wave-0 body is byte-identical to r12 (fastest per-step measured: 39.4
// cy/step); ONLY the chunk geometry changed (252 -> 480) to amortize the
// per-chunk fixed cost (barrier drain + copy latency + bits tail).
__launch_bounds__(192, 1)
__global__ void acs3_kernel(const float* __restrict__ q,
                            float* __restrict__ out, int T, int nchunks) {
  __shared__ float q_lds[2][CFLOATS];       // 80 KB
  __shared__ float hist_lds[2][CHUNK][9];   // 33.8 KB (pad 9: conflict-free)
  __shared__ float junk[4400];              // 17.6 KB dead sink for non-dumpers
  const int tid = (int)threadIdx.x;
  const int lane = tid & 63;
  const int wid = tid >> 6;

  // ---- prologue: copy chunk 0 into q_lds[0] (all 192 threads) ----
  {
    const float4* src = (const float4*)q;
    float4* dst = (float4*)&q_lds[0][0];
    for (int i = tid; i < CFLOATS / 4; i += 192) dst[i] = src[i];
  }
  __syncthreads();

  // ---- per-lane butterfly constants (r8/r10-verified) ----
  const int i3 = (lane & 3) | ((lane >> 1) & 4);
  const int rotr_i = ((i3 >> 1) | (i3 << 2)) & 7;
  const int rotl_i = ((i3 << 1) | (i3 >> 2)) & 7;
  const int d0 = i3, d1 = rotr_i, d2 = rotl_i;   // pre-update state held
  const bool dumper = (lane < 16) && ((lane & 4) == 0);

  float w = 0.f;  // S[i] = u[i] at phase 0

  for (int c = 0; c < nchunks; ++c) {
    const int p = c & 1;

    if (wid == 0) {
      // ---- wave 0: serial butterfly over 160 triples (r12 body) ----
      const char* qptr = (const char*)(&q_lds[p][0] + i3 * 8);
      char* const hb = (char*)&hist_lds[p][0][0];
      char* const jb = (char*)junk + lane * 4;
      char* a0 = dumper ? hb + d0 * 4      : jb;
      char* a1 = dumper ? hb + 36 + d1 * 4 : jb + 36;
      char* a2 = dumper ? hb + 72 + d2 * 4 : jb + 72;

      float4 rA[4]; float2 rB[4];  // ring: 4 triples in flight
#pragma unroll
      for (int n = 0; n < 4; ++n) {
        rA[n] = *(const float4*)(qptr + n * 256);
        rB[n] = *(const float2*)(qptr + n * 256 + 16);
      }
      for (int it = 0; it < NTRIC / 4 - 1; ++it) {  // 39 iters: triples 0..155
#pragma unroll
        for (int n = 0; n < 4; ++n) {
          const float4 A = rA[n]; const float2 B = rB[n];
          rA[n] = *(const float4*)(qptr + (n + 4) * 256);
          rB[n] = *(const float2*)(qptr + (n + 4) * 256 + 16);
          *(float*)(a0 + n * 108) = w;
          { const float wp = DPP_SWAP(w, 0xB1);   // lane^1
            w = fminf(__fsub_rn(w, A.x), __fsub_rn(wp, A.y)); }
          *(float*)(a1 + n * 108) = w;
          { const float wp = DPP_SWAP(w, 0x4E);   // lane^2
            w = fminf(__fsub_rn(w, A.z), __fsub_rn(wp, A.w)); }
          *(float*)(a2 + n * 108) = w;
          { const float wp = DPP_SWAP(w, 0x128);  // lane^8 (row_ror:8)
            w = fminf(__fsub_rn(w, B.x), __fsub_rn(wp, B.y)); }
        }
        qptr += 1024; a0 += 432; a1 += 432; a2 += 432;
      }
#pragma unroll
      for (int n = 0; n < 4; ++n) {  // epilogue: triples 156..159, no reload
        const float4 A = rA[n]; const float2 B = rB[n];
        *(float*)(a0 + n * 108) = w;
        { const float wp = DPP_SWAP(w, 0xB1);
          w = fminf(__fsub_rn(w, A.x), __fsub_rn(wp, A.y)); }
        *(float*)(a1 + n * 108) = w;
        { const float wp = DPP_SWAP(w, 0x4E);
          w = fminf(__fsub_rn(w, A.z), __fsub_rn(wp, A.w)); }
        *(float*)(a2 + n * 108) = w;
        { const float wp = DPP_SWAP(w, 0x128);
          w = fminf(__fsub_rn(w, B.x), __fsub_rn(wp, B.y)); }
      }
    } else if (wid == 1) {
      // ---- wave 1: async copy chunk c+1 global -> q_lds[1-p] ----
      if (c + 1 < nchunks) {
        const float* srcbase = q + (size_t)(c + 1) * CFLOATS + lane * 4;
        float* const ldsbase = &q_lds[1 - p][0];
#pragma unroll
        for (int i = 0; i < CFLOATS / 256; ++i) {   // 40 x 1KB, all in flight
          GL2LDS(srcbase + i * 256, ldsbase + i * 256);
        }
        asm volatile("s_waitcnt vmcnt(0)" ::: "memory");
      }
    } else {
      // ---- wave 2: bits for chunk c-1 (strict-< first argmin) ----
      if (c > 0) {
        for (int tl = lane; tl < CHUNK; tl += 64) {
          const float* h = hist_lds[1 - p][tl];
          float m = h[0]; int arg = 0;
          if (h[1] < m) { m = h[1]; arg = 1; }
          if (h[2] < m) { m = h[2]; arg = 2; }
          if (h[3] < m) { m = h[3]; arg = 3; }
          if (h[4] < m) { m = h[4]; arg = 4; }
          if (h[5] < m) { m = h[5]; arg = 5; }
          if (h[6] < m) { m = h[6]; arg = 6; }
          if (h[7] < m) { m = h[7]; arg = 7; }
          out[(c - 1) * CHUNK + tl] = (float)(arg & 1);
        }
      }
    }
    __syncthreads();
  }

  // ---- epilogue: bits for the last chunk (all 192 threads) ----
  {
    const int c = nchunks - 1;
    const int p = c & 1;
    const int base = c * CHUNK;
    const int nsteps = T - base;
    for (int tl = tid; tl < nsteps; tl += 192) {
      const float* h = hist_lds[p][tl];
      float m = h[0]; int arg = 0;
      if (h[1] < m) { m = h[1]; arg = 1; }
      if (h[2] < m) { m = h[2]; arg = 2; }
      if (h[3] < m) { m = h[3]; arg = 3; }
      if (h[4] < m) { m = h[4]; arg = 4; }
      if (h[5] < m) { m = h[5]; arg = 5; }
      if (h[6] < m) { m = h[6]; arg = 6; }
      if (h[7] < m) { m = h[7]; arg = 7; }
      out[base + tl] = (float)(arg & 1);
    }
  }
}

// ---------- Fallback: round-8 single-kernel structure (PASSING lineage) -----
#define NPROD 960
__launch_bounds__(1024, 1)
__global__ void viterbi_bfly(const float* __restrict__ rx,
                             const float* __restrict__ W1,
                             const float* __restrict__ b1,
                             const float* __restrict__ W2,
                             const float* __restrict__ b2,
                             float* __restrict__ out, int T) {
  __shared__ float q_lds[2][CHUNK][NSTATE];
  __shared__ float hist[2][CHUNK][9];
  const int tid = (int)threadIdx.x;
  const int lane = tid & 63;
  const int j = tid & 15;
  const int nchunks = (T + CHUNK - 1) / CHUNK;
  {
    const int n0 = min(CHUNK, T);
    for (int id = tid; id < n0 * NSTATE; id += 1024) {
      const int tl = id >> 4;
      const float rxv = rx[tl];
      PRIOR_ONE(rxv, j, q_lds[0][tl][j]);
    }
  }
  __syncthreads();
  const int i3 = (lane & 3) | ((lane >> 1) & 4);
  const int rotr_i = ((i3 >> 1) | (i3 << 2)) & 7;
  const int rotl_i = ((i3 << 1) | (i3 >> 2)) & 7;
  const int s0 = rotr_i, s1 = rotl_i, s2 = i3;
  const int q0 = 2 * s0, q1 = 2 * s1, q2 = 2 * s2;
  const bool r0 = (s0 & 4) != 0, r1 = (s1 & 4) != 0, r2 = (s2 & 4) != 0;
  const int d0 = i3, d1 = rotr_i, d2 = rotl_i;
  const bool dumper = (lane < 16) && ((lane & 4) == 0);
  float w = 0.f;
  for (int c = 0; c < nchunks; ++c) {
    const int p = c & 1;
    const int base = c * CHUNK;
    const int nsteps = min(CHUNK, T - base);
    const int npad = ((nsteps + 2) / 3) * 3;
    if (tid < 64) {
      const float* qb = &q_lds[p][0][0];
      float2 f0 = *(const float2*)(qb + 0 * 16 + q0);
      float2 f1 = *(const float2*)(qb + 1 * 16 + q1);
      float2 f2 = *(const float2*)(qb + 2 * 16 + q2);
      for (int tl = 0; tl < npad; tl += 3) {
        const int nt = min(tl + 3, CHUNK - 3);
        float2 g0 = *(const float2*)(qb + (nt + 0) * 16 + q0);
        float2 g1 = *(const float2*)(qb + (nt + 1) * 16 + q1);
        float2 g2 = *(const float2*)(qb + (nt + 2) * 16 + q2);
        if (dumper) hist[p][tl][d0] = w;
        {
          const float wp = DPP_SWAP(w, 0xB1);
          const float we = r0 ? wp : w, wo = r0 ? w : wp;
          w = fminf(__fsub_rn(we, f0.x), __fsub_rn(wo, f0.y));
        }
        if (dumper) hist[p][tl + 1][d1] = w;
        {
          const float wp = DPP_SWAP(w, 0x4E);
          const float we = r1 ? wp : w, wo = r1 ? w : wp;
          w = fminf(__fsub_rn(we, f1.x), __fsub_rn(wo, f1.y));
        }
        if (dumper) hist[p][tl + 2][d2] = w;
        {
          const float wp = DPP_SWAP(w, 0x128);
          const float we = r2 ? wp : w, wo = r2 ? w : wp;
          w = fminf(__fsub_rn(we, f2.x), __fsub_rn(wo, f2.y));
        }
        f0 = g0; f1 = g1; f2 = g2;
      }
    } else {
      const int nc = c + 1;
      if (nc < nchunks) {
        const int nbase = nc * CHUNK;
        const int nn = min(CHUNK, T - nbase);
        for (int id = tid - 64; id < nn * NSTATE; id += NPROD) {
          const int tl = id >> 4;
          const float rxv = rx[nbase + tl];
          PRIOR_ONE(rxv, j, q_lds[1 - p][tl][j]);
        }
      }
      if (c > 0) {
        const int tl = tid - 64;
        if (tl < CHUNK) {
          const float* h = hist[1 - p][tl];
          float m = h[0]; int arg = 0;
          if (h[1] < m) { m = h[1]; arg = 1; }
          if (h[2] < m) { m = h[2]; arg = 2; }
          if (h[3] < m) { m = h[3]; arg = 3; }
          if (h[4] < m) { m = h[4]; arg = 4; }
          if (h[5] < m) { m = h[5]; arg = 5; }
          if (h[6] < m) { m = h[6]; arg = 6; }
          if (h[7] < m) { m = h[7]; arg = 7; }
          out[(c - 1) * CHUNK + tl] = (float)(arg & 1);
        }
      }
    }
    __syncthreads();
  }
  {
    const int c = nchunks - 1;
    const int p = c & 1;
    const int base = c * CHUNK;
    const int nsteps = T - base;
    if (tid < nsteps) {
      const float* h = hist[p][tid];
      float m = h[0]; int arg = 0;
      if (h[1] < m) { m = h[1]; arg = 1; }
      if (h[2] < m) { m = h[2]; arg = 2; }
      if (h[3] < m) { m = h[3]; arg = 3; }
      if (h[4] < m) { m = h[4]; arg = 4; }
      if (h[5] < m) { m = h[5]; arg = 5; }
      if (h[6] < m) { m = h[6]; arg = 6; }
      if (h[7] < m) { m = h[7]; arg = 7; }
      out[base + tid] = (float)(arg & 1);
    }
  }
}

extern "C" void kernel_launch(void* const* d_in, const int* in_sizes, int n_in,
                              void* d_out, int out_size, void* d_ws, size_t ws_size,
                              hipStream_t stream) {
  const float* rx = (const float*)d_in[0];
  const float* W1 = (const float*)d_in[1];
  const float* b1 = (const float*)d_in[2];
  const float* W2 = (const float*)d_in[3];
  const float* b2 = (const float*)d_in[4];
  float* out = (float*)d_out;
  const int T = in_sizes[0];

  const int nchunks = (T + CHUNK - 1) / CHUNK;
  const int tot = nchunks * CHUNK * NSTATE;              // K1 thread count
  const size_t need = (size_t)nchunks * CFLOATS * 4;     // full padded q size

  if (ws_size >= need) {
    float* qws = (float*)d_ws;
    priors_kernel<<<(tot + 255) / 256, 256, 0, stream>>>(
        rx, W1, b1, W2, b2, qws, T, tot);
    acs3_kernel<<<1, 192, 0, stream>>>(qws, out, T, nchunks);
  } else {
    viterbi_bfly<<<1, 1024, 0, stream>>>(rx, W1, b1, W2, b2, out, T);
  }
}

// Round 15
// 7473.379 us; speedup vs baseline: 1.2701x; 1.1054x over previous
//
#include <hip/hip_runtime.h>

#define NSTATE 16
#define H1 75
#define CHUNK 480            // 160 triples; %3==0, %16==0 (gl2lds), ring 4 | 160
#define NTRIC (CHUNK / 3)    // 160
#define CFLOATS (NTRIC * 64) // 10240 floats = 40 KB per buffer

// exact numpy-f32 prior: mul+add (NOT fma) layer 1, sequential-k FMA layer 2.
#define PRIOR_ONE(rxv, jj, dst)                               \
  {                                                           \
    float acc = 0.f;                                          \
    for (int k = 0; k < H1; ++k) {                            \
      float h = __fadd_rn(__fmul_rn((rxv), W1[k]), b1[k]);    \
      h = fmaxf(h, 0.f);                                      \
      acc = __fmaf_rn(h, W2[k * NSTATE + (jj)], acc);         \
    }                                                         \
    (dst) = __fadd_rn(acc, b2[(jj)]);                         \
  }

#define DPP_SWAP(x, CTRL) \
  __int_as_float(__builtin_amdgcn_mov_dpp(__float_as_int(x), (CTRL), 0xF, 0xF, true))

// async global->LDS, 16B per lane, wave-uniform LDS base (HW layout contract)
#define GL2LDS(g, l)                                              \
  __builtin_amdgcn_global_load_lds(                               \
      (const __attribute__((address_space(1))) void*)(g),         \
      (__attribute__((address_space(3))) void*)(l), 16, 0, 0)

// ---------- K1: priors, grid-wide, stored triple-blocked + pre-swapped -----
// (unchanged from r11..r14, all passing)
__global__ void priors_kernel(const float* __restrict__ rx,
                              const float* __restrict__ W1,
                              const float* __restrict__ b1,
                              const float* __restrict__ W2,
                              const float* __restrict__ b2,
                              float* __restrict__ q, int T, int tot) {
  const int id = blockIdx.x * 256 + threadIdx.x;  // id = t*16 + j
  if (id >= tot) return;
  const int t = id >> 4, j = id & 15;
  float val = 0.f;
  if (t < T) {
    const float rxv = rx[t];
    PRIOR_ONE(rxv, j, val);
  }
  const int n = t / 3, ph = t - 3 * n;
  const int s = j >> 1, b = j & 1, r = (s >> 2) & 1;
  const int i3 = (ph == 0) ? (((s << 1) | (s >> 2)) & 7)
               : (ph == 1) ? (((s >> 1) | (s << 2)) & 7) : s;
  const int slot = 2 * ph + (b ^ r);
  q[(size_t)n * 64 + i3 * 8 + slot] = val;
}

// ---------- K2: serial ACS + copy + bits, 3 waves ---------------------------
// wave 0: butterfly; hist dumps now go to a GLOBAL 2-deep ring (vmcnt queue,
//         fire-and-forget) so wave 0's lgkm queue holds ONLY the 8 ring
//         ds_reads -> precise lgkmcnt waits (the r12/r14 stall was the
//         inexpressible lgkmcnt>15 forcing a prefetch drain every triple).
//         All 64 lanes store unpredicated: equal-i3 lanes hold identical w,
//         same-address same-value collisions are deterministic.
// wave 1: async copy chunk c+1 global -> q_lds[1-p] (r12-proven).
// wave 2: bits for chunk c-1 from the global hist ring (L1-hot).
__launch_bounds__(192, 1)
__global__ void acs3_kernel(const float* __restrict__ q,
                            float* __restrict__ hist_g,
                            float* __restrict__ out, int T, int nchunks) {
  __shared__ float q_lds[2][CFLOATS];       // 80 KB
  const int tid = (int)threadIdx.x;
  const int lane = tid & 63;
  const int wid = tid >> 6;

  // ---- prologue: copy chunk 0 into q_lds[0] (all 192 threads) ----
  {
    const float4* src = (const float4*)q;
    float4* dst = (float4*)&q_lds[0][0];
    for (int i = tid; i < CFLOATS / 4; i += 192) dst[i] = src[i];
  }
  __syncthreads();

  // ---- per-lane butterfly constants (r8/r10-verified) ----
  const int i3 = (lane & 3) | ((lane >> 1) & 4);
  const int rotr_i = ((i3 >> 1) | (i3 << 2)) & 7;
  const int rotl_i = ((i3 << 1) | (i3 >> 2)) & 7;
  const int d0 = i3, d1 = rotr_i, d2 = rotl_i;   // pre-update state held

  float w = 0.f;  // S[i] = u[i] at phase 0

  for (int c = 0; c < nchunks; ++c) {
    const int p = c & 1;

    if (wid == 0) {
      // ---- wave 0: serial butterfly over 160 triples ----
      const char* qptr = (const char*)(&q_lds[p][0] + i3 * 8);
      float* hg = hist_g + (size_t)p * CHUNK * 8;   // hist[t][8], t*8+slot

      float4 rA[4]; float2 rB[4];  // ring: 4 triples in flight (reads only)
#pragma unroll
      for (int n = 0; n < 4; ++n) {
        rA[n] = *(const float4*)(qptr + n * 256);
        rB[n] = *(const float2*)(qptr + n * 256 + 16);
      }
      for (int it = 0; it < NTRIC / 4 - 1; ++it) {  // 39 iters: triples 0..155
#pragma unroll
        for (int n = 0; n < 4; ++n) {
          const float4 A = rA[n]; const float2 B = rB[n];
          rA[n] = *(const float4*)(qptr + (n + 4) * 256);
          rB[n] = *(const float2*)(qptr + (n + 4) * 256 + 16);
          hg[n * 24 + d0] = w;                    // pre-update u -> slot d0
          { const float wp = DPP_SWAP(w, 0xB1);   // lane^1
            w = fminf(__fsub_rn(w, A.x), __fsub_rn(wp, A.y)); }
          hg[n * 24 + 8 + d1] = w;
          { const float wp = DPP_SWAP(w, 0x4E);   // lane^2
            w = fminf(__fsub_rn(w, A.z), __fsub_rn(wp, A.w)); }
          hg[n * 24 + 16 + d2] = w;
          { const float wp = DPP_SWAP(w, 0x128);  // lane^8 (row_ror:8)
            w = fminf(__fsub_rn(w, B.x), __fsub_rn(wp, B.y)); }
        }
        qptr += 1024; hg += 96;
      }
#pragma unroll
      for (int n = 0; n < 4; ++n) {  // epilogue: triples 156..159, no reload
        const float4 A = rA[n]; const float2 B = rB[n];
        hg[n * 24 + d0] = w;
        { const float wp = DPP_SWAP(w, 0xB1);
          w = fminf(__fsub_rn(w, A.x), __fsub_rn(wp, A.y)); }
        hg[n * 24 + 8 + d1] = w;
        { const float wp = DPP_SWAP(w, 0x4E);
          w = fminf(__fsub_rn(w, A.z), __fsub_rn(wp, A.w)); }
        hg[n * 24 + 16 + d2] = w;
        { const float wp = DPP_SWAP(w, 0x128);
          w = fminf(__fsub_rn(w, B.x), __fsub_rn(wp, B.y)); }
      }
    } else if (wid == 1) {
      // ---- wave 1: async copy chunk c+1 global -> q_lds[1-p] ----
      if (c + 1 < nchunks) {
        const float* srcbase = q + (size_t)(c + 1) * CFLOATS + lane * 4;
        float* const ldsbase = &q_lds[1 - p][0];
#pragma unroll
        for (int i = 0; i < CFLOATS / 256; ++i) {   // 40 x 1KB, all in flight
          GL2LDS(srcbase + i * 256, ldsbase + i * 256);
        }
        asm volatile("s_waitcnt vmcnt(0)" ::: "memory");
      }
    } else {
      // ---- wave 2: bits for chunk c-1 (strict-< first argmin) ----
      if (c > 0) {
        const float* hg1 = hist_g + (size_t)(1 - p) * CHUNK * 8;
        for (int tl = lane; tl < CHUNK; tl += 64) {
          const float* h = hg1 + tl * 8;
          float m = h[0]; int arg = 0;
          if (h[1] < m) { m = h[1]; arg = 1; }
          if (h[2] < m) { m = h[2]; arg = 2; }
          if (h[3] < m) { m = h[3]; arg = 3; }
          if (h[4] < m) { m = h[4]; arg = 4; }
          if (h[5] < m) { m = h[5]; arg = 5; }
          if (h[6] < m) { m = h[6]; arg = 6; }
          if (h[7] < m) { m = h[7]; arg = 7; }
          out[(c - 1) * CHUNK + tl] = (float)(arg & 1);
        }
      }
    }
    __syncthreads();
  }

  // ---- epilogue: bits for the last chunk (all 192 threads) ----
  {
    const int c = nchunks - 1;
    const int p = c & 1;
    const int base = c * CHUNK;
    const int nsteps = T - base;
    const float* hg1 = hist_g + (size_t)p * CHUNK * 8;
    for (int tl = tid; tl < nsteps; tl += 192) {
      const float* h = hg1 + tl * 8;
      float m = h[0]; int arg = 0;
      if (h[1] < m) { m = h[1]; arg = 1; }
      if (h[2] < m) { m = h[2]; arg = 2; }
      if (h[3] < m) { m = h[3]; arg = 3; }
      if (h[4] < m) { m = h[4]; arg = 4; }
      if (h[5] < m) { m = h[5]; arg = 5; }
      if (h[6] < m) { m = h[6]; arg = 6; }
      if (h[7] < m) { m = h[7]; arg = 7; }
      out[base + tl] = (float)(arg & 1);
    }
  }
}

// ---------- Fallback: round-8 single-kernel structure (PASSING lineage) -----
#define NPROD 960
__launch_bounds__(1024, 1)
__global__ void viterbi_bfly(const float* __restrict__ rx,
                             const float* __restrict__ b1_,
                             const float* __restrict__ b1,
                             const float* __restrict__ W2,
                             const float* __restrict__ b2,
                             float* __restrict__ out, int T);
__launch_bounds__(1024, 1)
__global__ void viterbi_bfly(const float* __restrict__ rx,
                             const float* __restrict__ W1,
                             const float* __restrict__ b1,
                             const float* __restrict__ W2,
                             const float* __restrict__ b2,
                             float* __restrict__ out, int T) {
  __shared__ float q_lds[2][CHUNK][NSTATE];
  __shared__ float hist[2][CHUNK][9];
  const int tid = (int)threadIdx.x;
  const int lane = tid & 63;
  const int j = tid & 15;
  const int nchunks = (T + CHUNK - 1) / CHUNK;
  {
    const int n0 = min(CHUNK, T);
    for (int id = tid; id < n0 * NSTATE; id += 1024) {
      const int tl = id >> 4;
      const float rxv = rx[tl];
      PRIOR_ONE(rxv, j, q_lds[0][tl][j]);
    }
  }
  __syncthreads();
  const int i3 = (lane & 3) | ((lane >> 1) & 4);
  const int rotr_i = ((i3 >> 1) | (i3 << 2)) & 7;
  const int rotl_i = ((i3 << 1) | (i3 >> 2)) & 7;
  const int s0 = rotr_i, s1 = rotl_i, s2 = i3;
  const int q0 = 2 * s0, q1 = 2 * s1, q2 = 2 * s2;
  const bool r0 = (s0 & 4) != 0, r1 = (s1 & 4) != 0, r2 = (s2 & 4) != 0;
  const int d0 = i3, d1 = rotr_i, d2 = rotl_i;
  const bool dumper = (lane < 16) && ((lane & 4) == 0);
  float w = 0.f;
  for (int c = 0; c < nchunks; ++c) {
    const int p = c & 1;
    const int base = c * CHUNK;
    const int nsteps = min(CHUNK, T - base);
    const int npad = ((nsteps + 2) / 3) * 3;
    if (tid < 64) {
      const float* qb = &q_lds[p][0][0];
      float2 f0 = *(const float2*)(qb + 0 * 16 + q0);
      float2 f1 = *(const float2*)(qb + 1 * 16 + q1);
      float2 f2 = *(const float2*)(qb + 2 * 16 + q2);
      for (int tl = 0; tl < npad; tl += 3) {
        const int nt = min(tl + 3, CHUNK - 3);
        float2 g0 = *(const float2*)(qb + (nt + 0) * 16 + q0);
        float2 g1 = *(const float2*)(qb + (nt + 1) * 16 + q1);
        float2 g2 = *(const float2*)(qb + (nt + 2) * 16 + q2);
        if (dumper) hist[p][tl][d0] = w;
        {
          const float wp = DPP_SWAP(w, 0xB1);
          const float we = r0 ? wp : w, wo = r0 ? w : wp;
          w = fminf(__fsub_rn(we, f0.x), __fsub_rn(wo, f0.y));
        }
        if (dumper) hist[p][tl + 1][d1] = w;
        {
          const float wp = DPP_SWAP(w, 0x4E);
          const float we = r1 ? wp : w, wo = r1 ? w : wp;
          w = fminf(__fsub_rn(we, f1.x), __fsub_rn(wo, f1.y));
        }
        if (dumper) hist[p][tl + 2][d2] = w;
        {
          const float wp = DPP_SWAP(w, 0x128);
          const float we = r2 ? wp : w, wo = r2 ? w : wp;
          w = fminf(__fsub_rn(we, f2.x), __fsub_rn(wo, f2.y));
        }
        f0 = g0; f1 = g1; f2 = g2;
      }
    } else {
      const int nc = c + 1;
      if (nc < nchunks) {
        const int nbase = nc * CHUNK;
        const int nn = min(CHUNK, T - nbase);
        for (int id = tid - 64; id < nn * NSTATE; id += NPROD) {
          const int tl = id >> 4;
          const float rxv = rx[nbase + tl];
          PRIOR_ONE(rxv, j, q_lds[1 - p][tl][j]);
        }
      }
      if (c > 0) {
        const int tl = tid - 64;
        if (tl < CHUNK) {
          const float* h = hist[1 - p][tl];
          float m = h[0]; int arg = 0;
          if (h[1] < m) { m = h[1]; arg = 1; }
          if (h[2] < m) { m = h[2]; arg = 2; }
          if (h[3] < m) { m = h[3]; arg = 3; }
          if (h[4] < m) { m = h[4]; arg = 4; }
          if (h[5] < m) { m = h[5]; arg = 5; }
          if (h[6] < m) { m = h[6]; arg = 6; }
          if (h[7] < m) { m = h[7]; arg = 7; }
          out[(c - 1) * CHUNK + tl] = (float)(arg & 1);
        }
      }
    }
    __syncthreads();
  }
  {
    const int c = nchunks - 1;
    const int p = c & 1;
    const int base = c * CHUNK;
    const int nsteps = T - base;
    if (tid < nsteps) {
      const float* h = hist[p][tid];
      float m = h[0]; int arg = 0;
      if (h[1] < m) { m = h[1]; arg = 1; }
      if (h[2] < m) { m = h[2]; arg = 2; }
      if (h[3] < m) { m = h[3]; arg = 3; }
      if (h[4] < m) { m = h[4]; arg = 4; }
      if (h[5] < m) { m = h[5]; arg = 5; }
      if (h[6] < m) { m = h[6]; arg = 6; }
      if (h[7] < m) { m = h[7]; arg = 7; }
      out[base + tid] = (float)(arg & 1);
    }
  }
}

extern "C" void kernel_launch(void* const* d_in, const int* in_sizes, int n_in,
                              void* d_out, int out_size, void* d_ws, size_t ws_size,
                              hipStream_t stream) {
  const float* rx = (const float*)d_in[0];
  const float* W1 = (const float*)d_in[1];
  const float* b1 = (const float*)d_in[2];
  const float* W2 = (const float*)d_in[3];
  const float* b2 = (const float*)d_in[4];
  float* out = (float*)d_out;
  const int T = in_sizes[0];

  const int nchunks = (T + CHUNK - 1) / CHUNK;
  const int tot = nchunks * CHUNK * NSTATE;              // K1 thread count
  const size_t qfloats = (size_t)nchunks * CFLOATS;
  const size_t hfloats = (size_t)2 * CHUNK * 8;          // 2-deep global ring
  const size_t need = (qfloats + hfloats) * 4;

  if (ws_size >= need) {
    float* qws = (float*)d_ws;
    float* hist_g = qws + qfloats;
    priors_kernel<<<(tot + 255) / 256, 256, 0, stream>>>(
        rx, W1, b1, W2, b2, qws, T, tot);
    acs3_kernel<<<1, 192, 0, stream>>>(qws, hist_g, out, T, nchunks);
  } else {
    viterbi_bfly<<<1, 1024, 0, stream>>>(rx, W1, b1, W2, b2, out, T);
  }
}